// Round 1
// baseline (218.708 us; speedup 1.0000x reference)
//
#include <hip/hip_runtime.h>
#include <hip/hip_bf16.h>

#define H 1024
#define NTMAX 4096

__global__ __launch_bounds__(1024) void euler_pwl_kernel(
    const float* __restrict__ x0p, const float* __restrict__ dtp,
    const int*   __restrict__ ntp,
    const float* __restrict__ W1, const float* __restrict__ b1,
    const float* __restrict__ W2, const float* __restrict__ b2p,
    float* __restrict__ out)
{
    __shared__ float s_t[H + 2];      // sentinel layout: s_t[0]=-inf, s_t[1..H]=sorted keys, s_t[H+1]=+inf
    __shared__ float s_c[H + 1];      // per-segment c = 1 + dt*A
    __shared__ float s_d[H + 1];      // per-segment d = dt*B
    __shared__ float s_key[H];
    __shared__ float s_da[H];
    __shared__ float s_dc[H];
    __shared__ float s_r1[H];
    __shared__ float s_r2[H];
    __shared__ float s_out[NTMAX];
    __shared__ int   s_seg;

    const int tid = threadIdx.x;
    const float dt = dtp[0];
    const float x0 = x0p[0];
    int nt = ntp[0];
    if (nt > NTMAX) nt = NTMAX;       // defensive: LDS sizing
    const float b2 = b2p[0];
    const float INF = __builtin_huge_valf();

    // ---- per-unit setup ----
    // unit j contributes relu(w1*x + b1)*w2.  breakpoint t = -b1/w1.
    //   w1 > 0: active for x > t   -> crossing t upward adds (+a, +cc)
    //   w1 < 0: active for x < t   -> crossing t upward adds (-a, -cc); active at x=-inf
    //   w1 == 0: constant relu(b1)*w2 added to base intercept
    {
        float w1 = W1[tid], bb = b1[tid], w2 = W2[tid];
        float a  = w1 * w2;
        float cc = bb * w2;
        float key, da, dc, r1, r2;
        if (w1 > 0.0f)      { key = -bb / w1; da =  a; dc =  cc; r1 = 0.0f; r2 = 0.0f; }
        else if (w1 < 0.0f) { key = -bb / w1; da = -a; dc = -cc; r1 = a;    r2 = cc;   }
        else                { key = INF;      da = 0.0f; dc = 0.0f; r1 = 0.0f; r2 = fmaxf(bb, 0.0f) * w2; }
        s_key[tid] = key; s_da[tid] = da; s_dc[tid] = dc;
        s_r1[tid] = r1;   s_r2[tid] = r2;
    }
    __syncthreads();

    // ---- block reduce: A0 = sum(neg-unit slopes), B0 = b2 + sum(neg intercepts + const units) ----
    for (int off = H / 2; off > 0; off >>= 1) {
        if (tid < off) { s_r1[tid] += s_r1[tid + off]; s_r2[tid] += s_r2[tid + off]; }
        __syncthreads();
    }
    const float A0 = s_r1[0];
    const float B0 = b2 + s_r2[0];
    __syncthreads();

    // ---- bitonic sort (key, da, dc) ascending by key ----
    for (int k = 2; k <= H; k <<= 1) {
        for (int j = k >> 1; j > 0; j >>= 1) {
            int ixj = tid ^ j;
            if (ixj > tid) {
                bool up = ((tid & k) == 0);
                float k0 = s_key[tid], k1 = s_key[ixj];
                bool sw = up ? (k0 > k1) : (k0 < k1);
                if (sw) {
                    s_key[tid] = k1; s_key[ixj] = k0;
                    float t0;
                    t0 = s_da[tid]; s_da[tid] = s_da[ixj]; s_da[ixj] = t0;
                    t0 = s_dc[tid]; s_dc[tid] = s_dc[ixj]; s_dc[ixj] = t0;
                }
            }
            __syncthreads();
        }
    }

    // ---- inclusive prefix sums over sorted deltas (Hillis-Steele) ----
    for (int off = 1; off < H; off <<= 1) {
        float va = 0.0f, vc = 0.0f;
        if (tid >= off) { va = s_da[tid - off]; vc = s_dc[tid - off]; }
        __syncthreads();
        s_da[tid] += va; s_dc[tid] += vc;
        __syncthreads();
    }

    // ---- build segment tables ----
    // segment i (0..H) covers [s_t[i], s_t[i+1]);  A_i = A0 + (i==0 ? 0 : prefix[i-1])
    s_t[tid + 1] = s_key[tid];
    {
        float Ai = A0 + s_da[tid];            // segment tid+1
        float Bi = B0 + s_dc[tid];
        s_c[tid + 1] = fmaf(dt, Ai, 1.0f);
        s_d[tid + 1] = dt * Bi;
    }
    if (tid == 0) {
        s_t[0] = -INF; s_t[H + 1] = INF;
        s_c[0] = fmaf(dt, A0, 1.0f);
        s_d[0] = dt * B0;
    }
    __syncthreads();

    // ---- find initial segment in parallel ----
    if (x0 >= s_t[tid] && x0 < s_t[tid + 1]) s_seg = tid;
    if (tid == 0 && x0 >= s_t[H] && x0 < s_t[H + 1]) s_seg = H;
    __syncthreads();

    // ---- serial Euler walk (thread 0) ----
    if (tid == 0) {
        int i = s_seg;
        float c = s_c[i], d = s_d[i];
        float lo = s_t[i], hi = s_t[i + 1];
        float x = x0;
        s_out[0] = x;
        for (int k = 1; k < nt; ++k) {
            x = fmaf(c, x, d);
            s_out[k] = x;
            if (x < lo || x >= hi) {
                while (x >= s_t[i + 1]) ++i;   // sentinels guarantee termination
                while (x <  s_t[i])     --i;
                lo = s_t[i]; hi = s_t[i + 1];
                c = s_c[i]; d = s_d[i];
            }
        }
    }
    __syncthreads();

    // ---- coalesced writeback ----
    for (int k = tid; k < nt; k += H) out[k] = s_out[k];
}

extern "C" void kernel_launch(void* const* d_in, const int* in_sizes, int n_in,
                              void* d_out, int out_size, void* d_ws, size_t ws_size,
                              hipStream_t stream) {
    const float* x0 = (const float*)d_in[0];
    const float* dt = (const float*)d_in[1];
    const int*   nt = (const int*)  d_in[2];
    const float* W1 = (const float*)d_in[3];
    const float* b1 = (const float*)d_in[4];
    const float* W2 = (const float*)d_in[5];
    const float* b2 = (const float*)d_in[6];
    float* out = (float*)d_out;
    euler_pwl_kernel<<<1, H, 0, stream>>>(x0, dt, nt, W1, b1, W2, b2, out);
}

// Round 2
// 41.121 us; speedup vs baseline: 5.3186x; 5.3186x over previous
//
#include <hip/hip_runtime.h>
#include <hip/hip_bf16.h>

#define H 1024
#define MAXRUNS 512

__global__ __launch_bounds__(1024) void euler_pwl_kernel(
    const float* __restrict__ x0p, const float* __restrict__ dtp,
    const int*   __restrict__ ntp,
    const float* __restrict__ W1, const float* __restrict__ b1,
    const float* __restrict__ W2, const float* __restrict__ b2p,
    float* __restrict__ out)
{
    __shared__ float s_t[H + 2];      // s_t[0]=-inf, s_t[1..H]=sorted keys, s_t[H+1]=+inf
    __shared__ float s_c[H + 1];      // per-segment c = 1 + dt*A
    __shared__ float s_d[H + 1];      // per-segment d = dt*B
    __shared__ float s_key[H];
    __shared__ float s_da[H];
    __shared__ float s_dc[H];
    __shared__ float s_r1[H];
    __shared__ float s_r2[H];
    __shared__ int    s_k0[MAXRUNS];  // run r starts at step s_k0[r] (x known there)
    __shared__ double s_p0[MAXRUNS];  // geometric: x*      | linear: x_start
    __shared__ double s_p1[MAXRUNS];  // geometric: delta0  | linear: d
    __shared__ double s_p2[MAXRUNS];  // geometric: log2(c) | linear: unused
    __shared__ unsigned char s_lin[MAXRUNS];
    __shared__ int   s_nruns;
    __shared__ int   s_fill_end;
    __shared__ int   s_seg;

    const int tid = threadIdx.x;
    const float dt = dtp[0];
    const float x0 = x0p[0];
    const int nt = ntp[0];
    const float b2 = b2p[0];
    const float INF = __builtin_huge_valf();

    // ---- per-unit setup ----
    {
        float w1 = W1[tid], bb = b1[tid], w2 = W2[tid];
        float a  = w1 * w2;
        float cc = bb * w2;
        float key, da, dc, r1, r2;
        if (w1 > 0.0f)      { key = -bb / w1; da =  a; dc =  cc; r1 = 0.0f; r2 = 0.0f; }
        else if (w1 < 0.0f) { key = -bb / w1; da = -a; dc = -cc; r1 = a;    r2 = cc;   }
        else                { key = INF;      da = 0.0f; dc = 0.0f; r1 = 0.0f; r2 = fmaxf(bb, 0.0f) * w2; }
        s_key[tid] = key; s_da[tid] = da; s_dc[tid] = dc;
        s_r1[tid] = r1;   s_r2[tid] = r2;
    }
    __syncthreads();

    // ---- block reduce: A0, B0 (all-negative-slope base + const units) ----
    for (int off = H / 2; off > 0; off >>= 1) {
        if (tid < off) { s_r1[tid] += s_r1[tid + off]; s_r2[tid] += s_r2[tid + off]; }
        __syncthreads();
    }
    const float A0 = s_r1[0];
    const float B0 = b2 + s_r2[0];
    __syncthreads();

    // ---- bitonic sort (key, da, dc) ascending by key ----
    for (int k = 2; k <= H; k <<= 1) {
        for (int j = k >> 1; j > 0; j >>= 1) {
            int ixj = tid ^ j;
            if (ixj > tid) {
                bool up = ((tid & k) == 0);
                float k0 = s_key[tid], k1 = s_key[ixj];
                bool sw = up ? (k0 > k1) : (k0 < k1);
                if (sw) {
                    s_key[tid] = k1; s_key[ixj] = k0;
                    float t0;
                    t0 = s_da[tid]; s_da[tid] = s_da[ixj]; s_da[ixj] = t0;
                    t0 = s_dc[tid]; s_dc[tid] = s_dc[ixj]; s_dc[ixj] = t0;
                }
            }
            __syncthreads();
        }
    }

    // ---- inclusive prefix sums (Hillis-Steele) ----
    for (int off = 1; off < H; off <<= 1) {
        float va = 0.0f, vc = 0.0f;
        if (tid >= off) { va = s_da[tid - off]; vc = s_dc[tid - off]; }
        __syncthreads();
        s_da[tid] += va; s_dc[tid] += vc;
        __syncthreads();
    }

    // ---- segment tables ----
    s_t[tid + 1] = s_key[tid];
    {
        float Ai = A0 + s_da[tid];
        float Bi = B0 + s_dc[tid];
        s_c[tid + 1] = fmaf(dt, Ai, 1.0f);
        s_d[tid + 1] = dt * Bi;
    }
    if (tid == 0) {
        s_t[0] = -INF; s_t[H + 1] = INF;
        s_c[0] = fmaf(dt, A0, 1.0f);
        s_d[0] = dt * B0;
    }
    __syncthreads();

    // ---- find initial segment ----
    if (x0 >= s_t[tid] && x0 < s_t[tid + 1]) s_seg = tid;
    if (tid == 0 && x0 >= s_t[H] && x0 < s_t[H + 1]) s_seg = H;
    __syncthreads();

    // ---- serial EVENT walk (thread 0): one iteration per segment-run ----
    if (tid == 0) {
        const int last = nt - 1;
        int i = s_seg;
        double x = (double)x0;
        int k = 0, r = 0;
        int fill_end = 0;
        while (k < last) {
            if (r >= MAXRUNS) {
                // correctness fallback: finish serially (round-1 semantics)
                float xf = (float)x;
                float lo = s_t[i], hi = s_t[i + 1];
                float cf = s_c[i], df = s_d[i];
                for (int kk = k + 1; kk <= last; ++kk) {
                    xf = fmaf(cf, xf, df);
                    out[kk] = xf;
                    if (xf < lo || xf >= hi) {
                        while (xf >= s_t[i + 1]) ++i;
                        while (xf <  s_t[i])     --i;
                        lo = s_t[i]; hi = s_t[i + 1]; cf = s_c[i]; df = s_d[i];
                    }
                }
                fill_end = k;
                k = last;
                break;
            }
            float cf = s_c[i], df = s_d[i];
            double c = (double)cf, d = (double)df;
            double lo = (double)s_t[i], hi = (double)s_t[i + 1];
            int remaining = last - k;
            int m;
            bool lin = (cf == 1.0f);
            double p0, p1, p2;
            if (lin) {
                p0 = x; p1 = d; p2 = 0.0;
                if (d == 0.0) m = remaining;
                else {
                    double mm = (d > 0.0) ? (hi - x) / d : (lo - x) / d;
                    m = (int)ceil(mm);
                    if (m < 1) m = 1;
                    if (m > remaining) m = remaining;
                    int guard = 0;
                    while (guard++ < 6 && m < remaining) {
                        double xm = fma((double)m, d, x);
                        if (xm >= hi || xm < lo) break;
                        ++m;
                    }
                }
            } else {
                double one_m_c = 1.0 - c;          // exact in fp64 (c is fp32)
                double xs = d / one_m_c;
                double delta = x - xs;
                double l2c = log2(c);
                p0 = xs; p1 = delta; p2 = l2c;
                double dirv = delta * (c - 1.0);   // sign of per-step motion
                if (delta == 0.0 || dirv == 0.0) m = remaining;
                else {
                    double T = (dirv > 0.0) ? hi : lo;
                    double ratio = (T - xs) / delta;
                    bool exits = (c > 1.0) ? true : (ratio > 0.0 && ratio < 1.0);
                    if (!exits) m = remaining;
                    else {
                        double mm = log2(ratio) / l2c;
                        m = (int)ceil(mm);
                        if (m < 1) m = 1;
                        if (m > remaining) m = remaining;
                        int guard = 0;
                        while (guard++ < 6 && m < remaining) {
                            double xm = xs + delta * exp2((double)m * l2c);
                            if (xm >= hi || xm < lo) break;
                            ++m;
                        }
                    }
                }
            }
            // record run r covering steps k+1 .. k+m
            s_k0[r] = k; s_p0[r] = p0; s_p1[r] = p1; s_p2[r] = p2;
            s_lin[r] = lin ? 1 : 0;
            ++r;
            // jump (identical expression to the fill phase -> exact run continuity)
            x = lin ? fma((double)m, p1, p0)
                    : (p0 + p1 * exp2((double)m * p2));
            k += m;
            fill_end = k;
            while (x >= (double)s_t[i + 1]) ++i;   // sentinels terminate
            while (x <  (double)s_t[i])     --i;
        }
        s_nruns = r;
        s_fill_end = fill_end;
    }
    __syncthreads();

    // ---- parallel closed-form fill ----
    {
        const int nruns = s_nruns;
        const int fend  = s_fill_end;
        for (int k = tid; k <= fend; k += H) {
            if (k == 0) { out[0] = x0; continue; }
            int loR = 0, hiR = nruns - 1;
            while (loR < hiR) {                     // largest r with s_k0[r] < k
                int mid = (loR + hiR + 1) >> 1;
                if (s_k0[mid] < k) loR = mid; else hiR = mid - 1;
            }
            int m = k - s_k0[loR];
            double v = s_lin[loR]
                     ? fma((double)m, s_p1[loR], s_p0[loR])
                     : (s_p0[loR] + s_p1[loR] * exp2((double)m * s_p2[loR]));
            out[k] = (float)v;
        }
    }
}

extern "C" void kernel_launch(void* const* d_in, const int* in_sizes, int n_in,
                              void* d_out, int out_size, void* d_ws, size_t ws_size,
                              hipStream_t stream) {
    const float* x0 = (const float*)d_in[0];
    const float* dt = (const float*)d_in[1];
    const int*   nt = (const int*)  d_in[2];
    const float* W1 = (const float*)d_in[3];
    const float* b1 = (const float*)d_in[4];
    const float* W2 = (const float*)d_in[5];
    const float* b2 = (const float*)d_in[6];
    float* out = (float*)d_out;
    euler_pwl_kernel<<<1, H, 0, stream>>>(x0, dt, nt, W1, b1, W2, b2, out);
}

// Round 3
// 37.673 us; speedup vs baseline: 5.8055x; 1.0915x over previous
//
#include <hip/hip_runtime.h>
#include <hip/hip_bf16.h>
#include <math.h>

#define H 1024
#define UPL 16            // units per lane (1024 units / 64 lanes)
#define MAXRUNS 1600

// Closed-form value of a geometric run: x_m = xs + delta * 2^(m*l2c).
// expm1-style branch avoids cancellation when xs is huge (near-linear segment).
// noinline => single instantiation => walk and fill agree bit-for-bit.
__device__ __attribute__((noinline)) double run_val(double xs, double delta, double l2c, double m) {
    double th = m * l2c;
    if (fabs(th) < 0.015) {
        double e = th * 0.6931471805599453094;   // th*ln2
        double g = e * (1.0 + e * (0.5 + e * (1.0/6.0 + e * (1.0/24.0 + e * (1.0/120.0)))));
        return (xs + delta) + delta * g;         // x_start + delta*(2^th - 1)
    }
    return xs + delta * (double)exp2f((float)th);
}

__device__ __attribute__((noinline)) double lin_val(double xstart, double d, double m) {
    return fma(m, d, xstart);
}

__global__ __launch_bounds__(1024) void euler_pwl_kernel(
    const float* __restrict__ x0p, const float* __restrict__ dtp,
    const int*   __restrict__ ntp,
    const float* __restrict__ W1, const float* __restrict__ b1,
    const float* __restrict__ W2, const float* __restrict__ b2p,
    float* __restrict__ out)
{
    __shared__ int    s_k0[MAXRUNS];
    __shared__ double s_p0[MAXRUNS];   // geom: xs      | lin: x_start
    __shared__ double s_p1[MAXRUNS];   // geom: delta   | lin: d
    __shared__ double s_p2[MAXRUNS];   // geom: log2(c) | lin: unused
    __shared__ unsigned char s_lin[MAXRUNS];
    __shared__ int s_nruns;
    __shared__ int s_fend;

    const int tid = threadIdx.x;
    const float dt  = dtp[0];
    const float x0f = x0p[0];
    const int   nt  = ntp[0];
    const float b2  = b2p[0];
    const float INFF = __builtin_huge_valf();
    const double DINF = __builtin_huge_val();

    if (tid < 64) {
        const int lane = tid;
        // ---- per-lane unit registers + initial (A,B) at x0 ----
        float tk[UPL], da[UPL], dc[UPL];
        double accA = 0.0, accB = 0.0;
        #pragma unroll
        for (int i = 0; i < UPL; ++i) {
            int u = i * 64 + lane;                 // coalesced
            float w1 = W1[u], bb = b1[u], w2 = W2[u];
            float a = w1 * w2, cc = bb * w2;
            float key, d_a, d_c, base_a = 0.0f, base_b = 0.0f;
            if (w1 > 0.0f)      { key = -bb / w1; d_a =  a; d_c =  cc; }
            else if (w1 < 0.0f) { key = -bb / w1; d_a = -a; d_c = -cc; base_a = a; base_b = cc; }
            else                { key = INFF;     d_a = 0.0f; d_c = 0.0f; base_b = fmaxf(bb, 0.0f) * w2; }
            tk[i] = key; da[i] = d_a; dc[i] = d_c;
            accA += (double)base_a; accB += (double)base_b;
            if (key <= x0f) { accA += (double)d_a; accB += (double)d_c; }
        }
        #pragma unroll
        for (int off = 32; off; off >>= 1) {
            accA += __shfl_xor(accA, off);
            accB += __shfl_xor(accB, off);
        }
        double A = accA, B = accB + (double)b2;   // identical on all lanes

        const double dtD = (double)dt;
        double x = (double)x0f;
        int k = 0, r = 0, fend = 0;
        const int last = nt - 1;

        // ---- event walk: one iteration per segment-run ----
        while (k < last && r < MAXRUNS) {
            double eps = dtD * A;                 // c - 1
            double d   = dtD * B;
            double v   = eps * x + d;             // per-step motion at x
            int remaining = last - k;
            int m, lin;
            double p0, p1, p2;

            if (v == 0.0) {
                lin = 1; p0 = x; p1 = 0.0; p2 = 0.0; m = remaining;
            } else {
                bool up = (v > 0.0);
                // nearest breakpoint strictly beyond x in motion direction
                double best = up ? DINF : -DINF;
                #pragma unroll
                for (int i = 0; i < UPL; ++i) {
                    double tv = (double)tk[i];
                    if (up)  { if (tv > x && tv < best) best = tv; }
                    else     { if (tv < x && tv > best) best = tv; }
                }
                #pragma unroll
                for (int off = 32; off; off >>= 1) {
                    double o = __shfl_xor(best, off);
                    best = up ? fmin(best, o) : fmax(best, o);
                }
                double T = best;

                if (eps == 0.0) {
                    lin = 1; p0 = x; p1 = d; p2 = 0.0;
                    if (isinf(T)) m = remaining;
                    else {
                        double mm = (T - x) / d;
                        if (!(mm < (double)remaining)) m = remaining;
                        else { m = (int)ceil(mm); if (m < 1) m = 1; }
                        int g = 0;
                        while (m < remaining && g++ < 8) {
                            double y = lin_val(p0, p1, (double)m);
                            if (up ? (y >= T) : (y <= T)) break;
                            ++m;
                        }
                        g = 0;
                        while (m > 1 && g++ < 8) {
                            double y = lin_val(p0, p1, (double)(m - 1));
                            if (up ? (y >= T) : (y <= T)) --m; else break;
                        }
                    }
                } else {
                    lin = 0;
                    double xs = -d / eps;          // fixed point
                    double delta = x - xs;
                    double e = eps;                // log2(1+e) via series (|e| ~ 1e-4)
                    double l2c = (e - e * e * (0.5 - e * (1.0/3.0 - e * 0.25)))
                               * 1.4426950408889634074;
                    p0 = xs; p1 = delta; p2 = l2c;
                    if (isinf(T)) m = remaining;
                    else {
                        double ratio = (T - xs) / delta;
                        bool exits = (eps > 0.0) ? true : (ratio > 0.0 && ratio < 1.0);
                        if (!exits) m = remaining;
                        else {
                            double mm = (double)__log2f((float)ratio) / l2c;
                            if (!(mm < (double)remaining)) m = remaining;
                            else { m = (int)ceil(mm); if (m < 1) m = 1; }
                            int g = 0;
                            while (m < remaining && g++ < 8) {
                                double y = run_val(p0, p1, p2, (double)m);
                                if (up ? (y >= T) : (y <= T)) break;
                                ++m;
                            }
                            g = 0;
                            while (m > 1 && g++ < 8) {
                                double y = run_val(p0, p1, p2, (double)(m - 1));
                                if (up ? (y >= T) : (y <= T)) --m; else break;
                            }
                        }
                    }
                }
            }

            if (lane == 0) {
                s_k0[r] = k; s_p0[r] = p0; s_p1[r] = p1; s_p2[r] = p2;
                s_lin[r] = (unsigned char)lin;
            }
            ++r;
            double xn = lin ? lin_val(p0, p1, (double)m) : run_val(p0, p1, p2, (double)m);
            k += m; fend = k;

            if (k < last) {
                // flip all units whose breakpoints lie in the crossed interval
                double sA = 0.0, sB = 0.0;
                bool upm = (xn > x);
                #pragma unroll
                for (int i = 0; i < UPL; ++i) {
                    double tv = (double)tk[i];
                    bool in = upm ? (tv > x && tv <= xn) : (tv > xn && tv <= x);
                    if (in) { sA += (double)da[i]; sB += (double)dc[i]; }
                }
                #pragma unroll
                for (int off = 32; off; off >>= 1) {
                    sA += __shfl_xor(sA, off);
                    sB += __shfl_xor(sB, off);
                }
                if (upm) { A += sA; B += sB; } else { A -= sA; B -= sB; }
            }
            x = xn;
        }

        // ---- fallback (records exhausted — pathological only): serial, correct ----
        while (k < last) {
            double eps = dtD * A, d = dtD * B;
            double v = eps * x + d;
            double xn = x + v;
            ++k;
            if (lane == 0) out[k] = (float)xn;
            double sA = 0.0, sB = 0.0;
            bool upm = (xn > x);
            #pragma unroll
            for (int i = 0; i < UPL; ++i) {
                double tv = (double)tk[i];
                bool in = upm ? (tv > x && tv <= xn) : (tv > xn && tv <= x);
                if (in) { sA += (double)da[i]; sB += (double)dc[i]; }
            }
            #pragma unroll
            for (int off = 32; off; off >>= 1) {
                sA += __shfl_xor(sA, off);
                sB += __shfl_xor(sB, off);
            }
            if (upm) { A += sA; B += sB; } else { A -= sA; B -= sB; }
            x = xn;
        }

        if (lane == 0) { s_nruns = r; s_fend = fend; }
    }
    __syncthreads();

    // ---- parallel closed-form fill ----
    {
        const int nruns = s_nruns;
        const int fend  = s_fend;
        for (int kk = tid; kk <= fend; kk += H) {
            if (kk == 0) { out[0] = x0f; continue; }
            int lo = 0, hi = nruns - 1;
            while (lo < hi) {                       // largest r with s_k0[r] < kk
                int mid = (lo + hi + 1) >> 1;
                if (s_k0[mid] < kk) lo = mid; else hi = mid - 1;
            }
            double m = (double)(kk - s_k0[lo]);
            double vv = s_lin[lo] ? lin_val(s_p0[lo], s_p1[lo], m)
                                  : run_val(s_p0[lo], s_p1[lo], s_p2[lo], m);
            out[kk] = (float)vv;
        }
    }
}

extern "C" void kernel_launch(void* const* d_in, const int* in_sizes, int n_in,
                              void* d_out, int out_size, void* d_ws, size_t ws_size,
                              hipStream_t stream) {
    const float* x0 = (const float*)d_in[0];
    const float* dt = (const float*)d_in[1];
    const int*   nt = (const int*)  d_in[2];
    const float* W1 = (const float*)d_in[3];
    const float* b1 = (const float*)d_in[4];
    const float* W2 = (const float*)d_in[5];
    const float* b2 = (const float*)d_in[6];
    float* out = (float*)d_out;
    euler_pwl_kernel<<<1, H, 0, stream>>>(x0, dt, nt, W1, b1, W2, b2, out);
}

// Round 4
// 32.093 us; speedup vs baseline: 6.8149x; 1.1739x over previous
//
#include <hip/hip_runtime.h>
#include <hip/hip_bf16.h>
#include <math.h>

#define UPL 16              // 1024 units / 64 lanes
#define MAXRUNS 512         // ws space; serial fallback if exceeded (never expected)

// ws layout (bytes): [0]=nruns(int) [4]=fend(int) [8..]=k0[512](int) lin[512](int)
// then doubles: p0[512] p1[512] p2[512].  Total 16392 B.
#define WS_K0(wsI)   ((wsI) + 2)
#define WS_LIN(wsI)  ((wsI) + 2 + MAXRUNS)
#define WS_DBASE     513    // (8 + 8*MAXRUNS)/8
#define WS_P0(wsD)   ((wsD) + WS_DBASE)
#define WS_P1(wsD)   ((wsD) + WS_DBASE + MAXRUNS)
#define WS_P2(wsD)   ((wsD) + WS_DBASE + 2*MAXRUNS)

// Geometric run value: x_m = xs + delta*e^(m*L).  Series path (expm1) avoids
// cancellation vs a distant fixed point; identical expression used by walk+fill.
__device__ inline double geo_val(double xs, double delta, double L, double m) {
    double t = m * L;
    if (fabs(t) < 0.03) {
        double g = t * (1.0 + t * (0.5 + t * (1.0/6.0 + t * (1.0/24.0 + t * (1.0/120.0 + t * (1.0/720.0))))));
        return (xs + delta) + delta * g;       // run-start x + delta*expm1(t)
    }
    return xs + delta * (double)__expf((float)t);
}
__device__ inline double lin_val(double xst, double d, double m) { return fma(m, d, xst); }

__global__ __launch_bounds__(64) void walk_kernel(
    const float* __restrict__ x0p, const float* __restrict__ dtp,
    const float* __restrict__ W1, const float* __restrict__ b1,
    const float* __restrict__ W2, const float* __restrict__ b2p,
    float* __restrict__ out, int* __restrict__ wsI, double* __restrict__ wsD, int nt)
{
    const int lane = threadIdx.x;
    const float INFF = __builtin_huge_valf();

    const float x0f = x0p[0];
    const float dtf = dtp[0];
    const float b2  = b2p[0];

    // ---- per-lane unit registers + initial (A,B) at x0 ----
    float tk[UPL], da[UPL], dc[UPL];
    double accA = 0.0, accB = 0.0;
    #pragma unroll
    for (int i = 0; i < UPL; ++i) {
        int u = i * 64 + lane;
        float w1 = W1[u], bb = b1[u], w2 = W2[u];
        float a = w1 * w2, cc = bb * w2;
        float key, d_a, d_c;
        if (w1 > 0.0f)      { key = -bb / w1; d_a =  a; d_c =  cc; }
        else if (w1 < 0.0f) { key = -bb / w1; d_a = -a; d_c = -cc; accA += (double)a; accB += (double)cc; }
        else                { key = INFF;     d_a = 0.0f; d_c = 0.0f; accB += (double)(fmaxf(bb, 0.0f) * w2); }
        tk[i] = key; da[i] = d_a; dc[i] = d_c;
        if (key <= x0f) { accA += (double)d_a; accB += (double)d_c; }
    }
    #pragma unroll
    for (int off = 32; off; off >>= 1) {
        accA += __shfl_xor(accA, off);
        accB += __shfl_xor(accB, off);
    }
    double A = accA, B = accB + (double)b2;     // uniform across lanes

    const double dt = (double)dtf;
    double x = (double)x0f;
    float  xf = x0f;
    int k = 0, r = 0, fend = 0;
    const int last = nt - 1;

    // ---- event walk: one iteration per segment-run ----
    while (k < last && r < MAXRUNS) {
        double eps = dt * A;                    // c - 1  (|eps| ~ 1e-4)
        double d   = dt * B;
        double v   = eps * x + d;               // per-step motion at x
        int remaining = last - k;
        int m, lin;
        double P0, P1, P2;

        if (v == 0.0) {
            lin = 1; P0 = x; P1 = 0.0; P2 = 0.0; m = remaining;
        } else {
            const bool up = (v > 0.0);
            // nearest breakpoint strictly beyond xf in motion direction (fp32)
            float best = up ? INFF : -INFF;
            #pragma unroll
            for (int i = 0; i < UPL; ++i) {
                float tv = tk[i];
                if (up)  { if (tv > xf && tv < best) best = tv; }
                else     { if (tv < xf && tv > best) best = tv; }
            }
            #pragma unroll
            for (int off = 32; off; off >>= 1) {
                float o = __shfl_xor(best, off);
                best = up ? fminf(best, o) : fmaxf(best, o);
            }
            const float T = best;
            const double Td = (double)T;

            if (eps == 0.0) {
                lin = 1; P0 = x; P1 = d; P2 = 0.0;
                if (isinf(T)) m = remaining;
                else {
                    double mm = (Td - x) / d;
                    m = (mm < (double)remaining) ? ((mm < 1.0) ? 1 : (int)ceil(mm)) : remaining;
                    int g = 0;
                    while (m < remaining && g++ < 8) { double y = lin_val(P0, P1, (double)m);     if (up ? (y >= Td) : (y <= Td)) break; ++m; }
                    g = 0;
                    while (m > 1 && g++ < 8)         { double y = lin_val(P0, P1, (double)(m-1)); if (up ? (y >= Td) : (y <= Td)) --m; else break; }
                }
            } else {
                lin = 0;
                double xs = -d / eps;           // fixed point
                double delta = x - xs;
                double L = eps * (1.0 - eps * (0.5 - eps * (1.0/3.0 - eps * 0.25)));  // log1p(eps)
                P0 = xs; P1 = delta; P2 = L;
                if (isinf(T)) m = remaining;
                else {
                    double u = (Td - x) / delta;               // ratio = 1 + u
                    bool exits = (eps > 0.0) ? true : (u > -1.0 && u < 0.0);
                    if (!exits) m = remaining;
                    else {
                        double lr = (fabs(u) <= 0.25)
                                  ? u * (1.0 - u * (0.5 - u * (1.0/3.0 - u * (0.25 - u * 0.2))))
                                  : (double)__logf((float)(1.0 + u));
                        double mm = lr / L;
                        m = (mm < (double)remaining) ? ((mm < 1.0) ? 1 : (int)ceil(mm)) : remaining;
                        int g = 0;
                        while (m < remaining && g++ < 8) { double y = geo_val(P0, P1, P2, (double)m);     if (up ? (y >= Td) : (y <= Td)) break; ++m; }
                        g = 0;
                        while (m > 1 && g++ < 8)         { double y = geo_val(P0, P1, P2, (double)(m-1)); if (up ? (y >= Td) : (y <= Td)) --m; else break; }
                    }
                }
            }
        }

        if (lane == 0) {
            WS_K0(wsI)[r] = k; WS_LIN(wsI)[r] = lin;
            WS_P0(wsD)[r] = P0; WS_P1(wsD)[r] = P1; WS_P2(wsD)[r] = P2;
        }
        ++r;
        double xn = lin ? lin_val(P0, P1, (double)m) : geo_val(P0, P1, P2, (double)m);
        k += m; fend = k;
        float xnf = (float)xn;

        if (k < last) {
            // flip every unit whose breakpoint lies in the crossed fp32 interval
            float sA = 0.0f, sB = 0.0f;
            bool upm = (xnf > xf);
            #pragma unroll
            for (int i = 0; i < UPL; ++i) {
                float tv = tk[i];
                bool in = upm ? (tv > xf && tv <= xnf) : (tv > xnf && tv <= xf);
                if (in) { sA += da[i]; sB += dc[i]; }
            }
            #pragma unroll
            for (int off = 32; off; off >>= 1) {
                sA += __shfl_xor(sA, off);
                sB += __shfl_xor(sB, off);
            }
            if (upm) { A += (double)sA; B += (double)sB; }
            else     { A -= (double)sA; B -= (double)sB; }
        }
        x = xn; xf = xnf;
    }

    // ---- fallback (records exhausted — pathological only): serial, direct out ----
    while (k < last) {
        double eps = dt * A, d = dt * B;
        double xn = x + (eps * x + d);
        ++k;
        if (lane == 0) out[k] = (float)xn;
        float xnf = (float)xn;
        float sA = 0.0f, sB = 0.0f;
        bool upm = (xnf > xf);
        #pragma unroll
        for (int i = 0; i < UPL; ++i) {
            float tv = tk[i];
            bool in = upm ? (tv > xf && tv <= xnf) : (tv > xnf && tv <= xf);
            if (in) { sA += da[i]; sB += dc[i]; }
        }
        #pragma unroll
        for (int off = 32; off; off >>= 1) {
            sA += __shfl_xor(sA, off);
            sB += __shfl_xor(sB, off);
        }
        if (upm) { A += (double)sA; B += (double)sB; }
        else     { A -= (double)sA; B -= (double)sB; }
        x = xn; xf = xnf;
    }

    if (lane == 0) { wsI[0] = r; wsI[1] = fend; }
}

__global__ __launch_bounds__(256) void fill_kernel(
    const float* __restrict__ x0p,
    const int* __restrict__ wsI, const double* __restrict__ wsD,
    float* __restrict__ out, int nt)
{
    __shared__ int    s_k0[MAXRUNS];
    __shared__ int    s_ln[MAXRUNS];
    __shared__ double s_p0[MAXRUNS];
    __shared__ double s_p1[MAXRUNS];
    __shared__ double s_p2[MAXRUNS];
    __shared__ int s_nr, s_fe;

    const int tid = threadIdx.x;
    if (tid == 0) { s_nr = wsI[0]; s_fe = wsI[1]; }
    __syncthreads();
    const int nr = s_nr, fend = s_fe;
    for (int i = tid; i < nr; i += 256) {
        s_k0[i] = WS_K0(wsI)[i]; s_ln[i] = WS_LIN(wsI)[i];
        s_p0[i] = WS_P0(wsD)[i]; s_p1[i] = WS_P1(wsD)[i]; s_p2[i] = WS_P2(wsD)[i];
    }
    __syncthreads();

    const int k = blockIdx.x * 256 + tid;
    if (k >= nt || k > fend) return;       // (fend, nt) written by walk fallback
    if (k == 0) { out[0] = x0p[0]; return; }

    int lo = 0, hi = nr - 1;
    while (lo < hi) {                      // largest r with k0[r] < k
        int mid = (lo + hi + 1) >> 1;
        if (s_k0[mid] < k) lo = mid; else hi = mid - 1;
    }
    double m = (double)(k - s_k0[lo]);
    double v = s_ln[lo] ? lin_val(s_p0[lo], s_p1[lo], m)
                        : geo_val(s_p0[lo], s_p1[lo], s_p2[lo], m);
    out[k] = (float)v;
}

extern "C" void kernel_launch(void* const* d_in, const int* in_sizes, int n_in,
                              void* d_out, int out_size, void* d_ws, size_t ws_size,
                              hipStream_t stream) {
    const float* x0 = (const float*)d_in[0];
    const float* dt = (const float*)d_in[1];
    const float* W1 = (const float*)d_in[3];
    const float* b1 = (const float*)d_in[4];
    const float* W2 = (const float*)d_in[5];
    const float* b2 = (const float*)d_in[6];
    float* out = (float*)d_out;
    int*    wsI = (int*)d_ws;
    double* wsD = (double*)d_ws;
    const int nt = out_size;               // == nt input (4096)

    walk_kernel<<<1, 64, 0, stream>>>(x0, dt, W1, b1, W2, b2, out, wsI, wsD, nt);
    fill_kernel<<<(nt + 255) / 256, 256, 0, stream>>>(x0, wsI, wsD, out, nt);
}

// Round 5
// 25.424 us; speedup vs baseline: 8.6025x; 1.2623x over previous
//
#include <hip/hip_runtime.h>
#include <math.h>

#define UPL 16          // 1024 units / 64 lanes
#define NTH 512         // 8 waves: wave 0 walks, all fill
#define MAXRUNS 512

// DPP move with old=v preserved on invalid lanes (bound_ctrl=false)
#define DPPMV(v, ctrl) __int_as_float(__builtin_amdgcn_update_dpp( \
    __float_as_int(v), __float_as_int(v), (ctrl), 0xf, 0xf, false))

__device__ inline float wave_min64(float v) {
    v = fminf(v, DPPMV(v, 0x111));   // row_shr:1
    v = fminf(v, DPPMV(v, 0x112));   // row_shr:2
    v = fminf(v, DPPMV(v, 0x114));   // row_shr:4
    v = fminf(v, DPPMV(v, 0x118));   // row_shr:8  -> lane15 of each row has row min
    v = fminf(v, DPPMV(v, 0x142));   // row_bcast:15 -> lane31/63 combine row pairs
    v = fminf(v, DPPMV(v, 0x143));   // row_bcast:31 -> lane63 has wave min
    return __int_as_float(__builtin_amdgcn_readlane(__float_as_int(v), 63));
}
__device__ inline float wave_max64(float v) {
    v = fmaxf(v, DPPMV(v, 0x111));
    v = fmaxf(v, DPPMV(v, 0x112));
    v = fmaxf(v, DPPMV(v, 0x114));
    v = fmaxf(v, DPPMV(v, 0x118));
    v = fmaxf(v, DPPMV(v, 0x142));
    v = fmaxf(v, DPPMV(v, 0x143));
    return __int_as_float(__builtin_amdgcn_readlane(__float_as_int(v), 63));
}

// x_m = xs + delta * 2^(m*L2).  Series (expm1) path avoids cancellation vs a
// distant fixed point; identical expression in walk and fill => exact continuity.
__device__ inline double geo_val(double xs, double delta, double L2, double m) {
    double t = m * L2;
    if (fabs(t) < 0.043) {
        double e = t * 0.6931471805599453094;     // t*ln2, |e|<0.03
        double g = e * (1.0 + e * (0.5 + e * (1.0/6.0 + e * (1.0/24.0 + e * (1.0/120.0 + e * (1.0/720.0))))));
        return (xs + delta) + delta * g;
    }
    return xs + delta * (double)exp2f((float)t);
}
__device__ inline double lin_val(double xst, double d, double m) { return fma(m, d, xst); }

__global__ __launch_bounds__(NTH) void euler_kernel(
    const float* __restrict__ x0p, const float* __restrict__ dtp,
    const float* __restrict__ W1, const float* __restrict__ b1,
    const float* __restrict__ W2, const float* __restrict__ b2p,
    float* __restrict__ out, int nt)
{
    __shared__ int    s_k0[MAXRUNS];
    __shared__ double s_p0[MAXRUNS], s_p1[MAXRUNS], s_p2[MAXRUNS];
    __shared__ unsigned char s_ln[MAXRUNS];
    __shared__ int s_nr, s_fe;

    const int tid = threadIdx.x;
    const float x0f = x0p[0];
    const float INFF = __builtin_huge_valf();

    if (tid < 64) {
        const int lane = tid;
        const float dtf = dtp[0], b2 = b2p[0];

        // ---- per-lane unit registers + initial (A,B) at x0 ----
        float tk[UPL], da[UPL], dc[UPL];
        double accA = 0.0, accB = 0.0;
        #pragma unroll
        for (int i = 0; i < UPL; ++i) {
            int u = i * 64 + lane;
            float w1 = W1[u], bb = b1[u], w2 = W2[u];
            float a = w1 * w2, cc = bb * w2;
            float key, d_a, d_c;
            if (w1 > 0.0f)      { key = -bb / w1; d_a =  a; d_c =  cc; }
            else if (w1 < 0.0f) { key = -bb / w1; d_a = -a; d_c = -cc; accA += (double)a; accB += (double)cc; }
            else                { key = INFF;     d_a = 0.0f; d_c = 0.0f; accB += (double)(fmaxf(bb, 0.0f) * w2); }
            tk[i] = key; da[i] = d_a; dc[i] = d_c;
            if (key <= x0f) { accA += (double)d_a; accB += (double)d_c; }
        }
        #pragma unroll
        for (int off = 32; off; off >>= 1) {
            accA += __shfl_xor(accA, off);
            accB += __shfl_xor(accB, off);
        }
        double A = accA, B = accB + (double)b2;

        const double dt = (double)dtf;
        double x = (double)x0f;
        float  xf = x0f;
        int k = 0, r = 0, fend = 0;
        const int last = nt - 1;

        // ---- event walk ----
        while (k < last && r < MAXRUNS) {
            double eps = dt * A, d = dt * B;
            double v = eps * x + d;
            int remaining = last - k;
            int m, lin; double P0, P1, P2;

            if (v == 0.0) { lin = 1; P0 = x; P1 = 0.0; P2 = 0.0; m = remaining; }
            else {
                const bool up = (v > 0.0);
                // nearest breakpoint beyond xf in motion direction: tree + DPP
                float T;
                if (up) {
                    float q0 = INFF, q1 = INFF, q2 = INFF, q3 = INFF;
                    #pragma unroll
                    for (int i = 0; i < UPL; i += 4) {
                        q0 = fminf(q0, (tk[i    ] > xf) ? tk[i    ] : INFF);
                        q1 = fminf(q1, (tk[i + 1] > xf) ? tk[i + 1] : INFF);
                        q2 = fminf(q2, (tk[i + 2] > xf) ? tk[i + 2] : INFF);
                        q3 = fminf(q3, (tk[i + 3] > xf) ? tk[i + 3] : INFF);
                    }
                    T = wave_min64(fminf(fminf(q0, q1), fminf(q2, q3)));
                } else {
                    float q0 = -INFF, q1 = -INFF, q2 = -INFF, q3 = -INFF;
                    #pragma unroll
                    for (int i = 0; i < UPL; i += 4) {
                        q0 = fmaxf(q0, (tk[i    ] < xf) ? tk[i    ] : -INFF);
                        q1 = fmaxf(q1, (tk[i + 1] < xf) ? tk[i + 1] : -INFF);
                        q2 = fmaxf(q2, (tk[i + 2] < xf) ? tk[i + 2] : -INFF);
                        q3 = fmaxf(q3, (tk[i + 3] < xf) ? tk[i + 3] : -INFF);
                    }
                    T = wave_max64(fmaxf(fmaxf(q0, q1), fmaxf(q2, q3)));
                }
                const double Td = (double)T;

                if (eps == 0.0) {               // cold path
                    lin = 1; P0 = x; P1 = d; P2 = 0.0;
                    if (isinf(T)) m = remaining;
                    else {
                        double mm = (Td - x) / d;
                        m = (mm < (double)remaining) ? ((mm < 1.0) ? 1 : (int)ceil(mm)) : remaining;
                        int g = 0;
                        while (m < remaining && g++ < 8) { double y = lin_val(P0, P1, (double)m);     if (up ? (y >= Td) : (y <= Td)) break; ++m; }
                        g = 0;
                        while (m > 1 && g++ < 8)         { double y = lin_val(P0, P1, (double)(m-1)); if (up ? (y >= Td) : (y <= Td)) --m; else break; }
                    }
                } else {
                    lin = 0;
                    // xs = -d/eps via rcp + 2 Newton (rel err ~1e-16)
                    double r0 = (double)__builtin_amdgcn_rcpf((float)eps);
                    r0 = r0 * (2.0 - eps * r0);
                    r0 = r0 * (2.0 - eps * r0);
                    double xs = -d * r0;
                    double delta = x - xs;
                    double L2 = eps * (1.0 - eps * (0.5 - eps * (1.0/3.0 - eps * 0.25)))
                              * 1.4426950408889634074;          // log2(1+eps)
                    P0 = xs; P1 = delta; P2 = L2;
                    if (isinf(T)) m = remaining;
                    else {
                        // fp32 estimate; guards fix +-1 and estimate noise
                        float uf  = (float)(Td - x) * __builtin_amdgcn_rcpf((float)delta);
                        float mmf = __log2f(1.0f + uf) / (float)L2;
                        // NaN/-inf (ratio<=0: never exits) falls through to m=remaining
                        if (!(mmf < (float)remaining)) m = remaining;
                        else m = (mmf < 1.0f) ? 1 : (int)ceilf(mmf);
                        double ym = geo_val(P0, P1, P2, (double)m);
                        int g = 0;
                        while (m < remaining && g++ < 8) {
                            if (up ? (ym >= Td) : (ym <= Td)) break;
                            ++m; ym = geo_val(P0, P1, P2, (double)m);
                        }
                        g = 0;
                        while (m > 1 && g++ < 8) {
                            double yp = geo_val(P0, P1, P2, (double)(m - 1));
                            if (up ? (yp >= Td) : (yp <= Td)) --m; else break;
                        }
                    }
                }
            }

            if (lane == 0) {
                s_k0[r] = k; s_ln[r] = (unsigned char)lin;
                s_p0[r] = P0; s_p1[r] = P1; s_p2[r] = P2;
            }
            ++r;
            double xn = lin ? lin_val(P0, P1, (double)m) : geo_val(P0, P1, P2, (double)m);
            k += m; fend = k;
            float xnf = (float)xn;

            if (k < last) {
                // flip units whose breakpoints lie in the crossed interval:
                // per-lane masked sums + ballot + gather (usually 1 lane set)
                float sA = 0.0f, sB = 0.0f; int cnt = 0;
                bool upm = (xnf > xf);
                #pragma unroll
                for (int i = 0; i < UPL; ++i) {
                    float tv = tk[i];
                    bool in = upm ? (tv > xf && tv <= xnf) : (tv > xnf && tv <= xf);
                    if (in) { sA += da[i]; sB += dc[i]; ++cnt; }
                }
                unsigned long long msk = __ballot(cnt > 0);
                double dsA = 0.0, dsB = 0.0;
                while (msk) {
                    int l = __ffsll(msk) - 1;
                    msk &= (msk - 1);
                    dsA += (double)__shfl(sA, l);
                    dsB += (double)__shfl(sB, l);
                }
                if (upm) { A += dsA; B += dsB; } else { A -= dsA; B -= dsB; }
            }
            x = xn; xf = xnf;
        }

        // ---- fallback (run table exhausted — pathological only): serial, direct out ----
        while (k < last) {
            double eps = dt * A, d = dt * B;
            double xn = x + (eps * x + d);
            ++k;
            if (lane == 0) out[k] = (float)xn;
            float xnf = (float)xn;
            float sA = 0.0f, sB = 0.0f;
            bool upm = (xnf > xf);
            #pragma unroll
            for (int i = 0; i < UPL; ++i) {
                float tv = tk[i];
                bool in = upm ? (tv > xf && tv <= xnf) : (tv > xnf && tv <= xf);
                if (in) { sA += da[i]; sB += dc[i]; }
            }
            #pragma unroll
            for (int off = 32; off; off >>= 1) {
                sA += __shfl_xor(sA, off);
                sB += __shfl_xor(sB, off);
            }
            if (upm) { A += (double)sA; B += (double)sB; }
            else     { A -= (double)sA; B -= (double)sB; }
            x = xn; xf = xnf;
        }

        if (lane == 0) { s_nr = r; s_fe = fend; }
    }
    __syncthreads();

    // ---- parallel closed-form fill (all 512 threads) ----
    {
        const int nr = s_nr, fe = s_fe;
        for (int kk = tid; kk <= fe; kk += NTH) {
            if (kk == 0) { out[0] = x0f; continue; }
            int lo = 0, hi = nr - 1;
            while (lo < hi) {                    // largest r with k0[r] < kk
                int mid = (lo + hi + 1) >> 1;
                if (s_k0[mid] < kk) lo = mid; else hi = mid - 1;
            }
            double m = (double)(kk - s_k0[lo]);
            double vv = s_ln[lo] ? lin_val(s_p0[lo], s_p1[lo], m)
                                 : geo_val(s_p0[lo], s_p1[lo], s_p2[lo], m);
            out[kk] = (float)vv;
        }
    }
}

extern "C" void kernel_launch(void* const* d_in, const int* in_sizes, int n_in,
                              void* d_out, int out_size, void* d_ws, size_t ws_size,
                              hipStream_t stream) {
    const float* x0 = (const float*)d_in[0];
    const float* dt = (const float*)d_in[1];
    const float* W1 = (const float*)d_in[3];
    const float* b1 = (const float*)d_in[4];
    const float* W2 = (const float*)d_in[5];
    const float* b2 = (const float*)d_in[6];
    float* out = (float*)d_out;
    const int nt = out_size;
    euler_kernel<<<1, NTH, 0, stream>>>(x0, dt, W1, b1, W2, b2, out, nt);
}